// Round 4
// baseline (390.748 us; speedup 1.0000x reference)
//
#include <hip/hip_runtime.h>
#include <hip/hip_bf16.h>
#include <math.h>

#define CH 256
#define SCAN_BLOCK 1024

typedef short bf16x8 __attribute__((ext_vector_type(8)));
typedef float f32x4 __attribute__((ext_vector_type(4)));

__device__ __forceinline__ float lrelu(float v) { return fmaxf(v, 0.2f * v); }
__device__ __forceinline__ float elu(float v)   { return v > 0.f ? v : __expf(v) - 1.f; }

__device__ __forceinline__ unsigned short f2bf(float f) {
    unsigned u = __float_as_uint(f);
    return (unsigned short)((u + 0x7fffu + ((u >> 16) & 1u)) >> 16);
}
__device__ __forceinline__ float4 ldbf4(const unsigned short* rowbase, int lane) {
    uint2 u = ((const uint2*)rowbase)[lane];
    return make_float4(__uint_as_float(u.x << 16), __uint_as_float(u.x & 0xffff0000u),
                       __uint_as_float(u.y << 16), __uint_as_float(u.y & 0xffff0000u));
}
__device__ __forceinline__ void stbf4(unsigned short* rowbase, int lane, float4 v) {
    uint2 u;
    u.x = (unsigned)f2bf(v.x) | ((unsigned)f2bf(v.y) << 16);
    u.y = (unsigned)f2bf(v.z) | ((unsigned)f2bf(v.w) << 16);
    ((uint2*)rowbase)[lane] = u;
}

// ---------------- GEMM1: x (n x 20) @ W (20 x 256) + b -> bf16 xl, xr ----------------
__global__ __launch_bounds__(256) void gemm1_kernel(const float* __restrict__ x,
                             const float* __restrict__ Wl, const float* __restrict__ bl,
                             const float* __restrict__ Wr, const float* __restrict__ br,
                             unsigned short* __restrict__ xl, unsigned short* __restrict__ xr, int n) {
    __shared__ float xs[64][20];
    int n0 = blockIdx.x * 64;
    int tid = threadIdx.x;
    for (int i = tid; i < 64 * 20; i += 256) {
        int m = i / 20, k = i % 20;
        int row = n0 + m;
        xs[m][k] = (row < n) ? x[(size_t)row * 20 + k] : 0.f;
    }
    int c = tid;
    float wl[20], wr[20];
#pragma unroll
    for (int k = 0; k < 20; ++k) { wl[k] = Wl[k * 256 + c]; wr[k] = Wr[k * 256 + c]; }
    float blv = bl[c], brv = br[c];
    __syncthreads();
#pragma unroll 1
    for (int g = 0; g < 8; ++g) {
        int base = g * 8;
        float al[8], ar[8];
#pragma unroll
        for (int m = 0; m < 8; ++m) { al[m] = blv; ar[m] = brv; }
#pragma unroll
        for (int k = 0; k < 20; ++k) {
            float wlv = wl[k], wrv = wr[k];
#pragma unroll
            for (int m = 0; m < 8; ++m) {
                float xv = xs[base + m][k];
                al[m] += xv * wlv;
                ar[m] += xv * wrv;
            }
        }
#pragma unroll
        for (int m = 0; m < 8; ++m) {
            int row = n0 + base + m;
            if (row < n) {
                xl[(size_t)row * 256 + c] = f2bf(al[m]);
                xr[(size_t)row * 256 + c] = f2bf(ar[m]);
            }
        }
    }
}

// ---------------- CSR build ----------------
__global__ void count_deg(const int* __restrict__ ei, int* __restrict__ deg, int e) {
    int t = blockIdx.x * blockDim.x + threadIdx.x;
    if (t < e) atomicAdd(&deg[ei[e + t]], 1);
}

__global__ void scan_block_k(const int* __restrict__ deg, int* __restrict__ rowptr,
                             int* __restrict__ bsums, int n) {
    __shared__ int wsum[16];
    __shared__ int woff[17];
    int tid = threadIdx.x;
    int gi = blockIdx.x * SCAN_BLOCK + tid;
    int lane = tid & 63, wid = tid >> 6;
    int v = (gi < n) ? deg[gi] : 0;
    int incl = v;
#pragma unroll
    for (int d = 1; d < 64; d <<= 1) {
        int t = __shfl_up(incl, d, 64);
        if (lane >= d) incl += t;
    }
    if (lane == 63) wsum[wid] = incl;
    __syncthreads();
    if (tid < 16) {
        int s = wsum[tid];
#pragma unroll
        for (int d = 1; d < 16; d <<= 1) {
            int t = __shfl_up(s, d, 64);
            if (tid >= d) s += t;
        }
        woff[tid + 1] = s;
        if (tid == 0) woff[0] = 0;
    }
    __syncthreads();
    incl += woff[wid];
    if (gi < n) rowptr[gi + 1] = incl;
    if (tid == 0) bsums[blockIdx.x] = woff[16];
}

__global__ void scan_tops_k(int* bsums, int nb) {
    int tid = threadIdx.x;
    int v = (tid < nb) ? bsums[tid] : 0;
    int incl = v;
#pragma unroll
    for (int d = 1; d < 64; d <<= 1) {
        int t = __shfl_up(incl, d, 64);
        if (tid >= d) incl += t;
    }
    if (tid < nb) bsums[tid] = incl - v;
}

__global__ void scan_fix_k(int* __restrict__ rowptr, int* __restrict__ cursor,
                           const int* __restrict__ deg, const int* __restrict__ bsums, int n) {
    int gi = blockIdx.x * SCAN_BLOCK + threadIdx.x;
    if (gi >= n) return;
    int off = bsums[blockIdx.x];
    int incl = rowptr[gi + 1] + off;
    rowptr[gi + 1] = incl;
    cursor[gi] = incl - deg[gi];
    if (gi == 0) rowptr[0] = 0;
}

__global__ void scatter_k(const int* __restrict__ ei, int* __restrict__ cursor,
                          int* __restrict__ csr, int e) {
    int t = blockIdx.x * blockDim.x + threadIdx.x;
    if (t >= e) return;
    int s = ei[t], d = ei[e + t];
    int idx = atomicAdd(&cursor[d], 1);
    csr[idx] = s;
}

// ---------------- Fused GATv2 layer 1 (bf16 in, bf16 out), 8-edge batched ----------------
__global__ void fused_gat1(const unsigned short* __restrict__ xl, const unsigned short* __restrict__ xr,
                           const int* __restrict__ rowptr, const int* __restrict__ csr,
                           const float* __restrict__ att, const float* __restrict__ bias,
                           unsigned short* __restrict__ hout, int n) {
    int wid = threadIdx.x >> 6;
    int lane = threadIdx.x & 63;
    int i = blockIdx.x * 4 + wid;
    if (i >= n) return;
    float4 xr4 = ldbf4(xr + (size_t)i * CH, lane);
    float4 a4  = ((const float4*)att)[lane];
    float4 xli = ldbf4(xl + (size_t)i * CH, lane);
    float ps = lrelu(xli.x + xr4.x) * a4.x + lrelu(xli.y + xr4.y) * a4.y +
               lrelu(xli.z + xr4.z) * a4.z + lrelu(xli.w + xr4.w) * a4.w;
    ps += __shfl_xor(ps, 1); ps += __shfl_xor(ps, 2);
    ps += __shfl_xor(ps, 4); ps += __shfl_xor(ps, 8);
    float m = ps, l = 1.f;
    float4 acc = xli;
    int beg = rowptr[i], end = rowptr[i + 1];
    for (int e = beg; e < end; e += 8) {
        int cnt = end - e;
        int ss[8];
#pragma unroll
        for (int j = 0; j < 8; ++j) ss[j] = (j < cnt) ? csr[e + j] : i;
        float4 rr[8];
#pragma unroll
        for (int j = 0; j < 8; ++j) rr[j] = ldbf4(xl + (size_t)ss[j] * CH, lane);
        float pp[8];
#pragma unroll
        for (int j = 0; j < 8; ++j)
            pp[j] = lrelu(rr[j].x + xr4.x) * a4.x + lrelu(rr[j].y + xr4.y) * a4.y +
                    lrelu(rr[j].z + xr4.z) * a4.z + lrelu(rr[j].w + xr4.w) * a4.w;
#pragma unroll
        for (int d = 1; d < 16; d <<= 1)
#pragma unroll
            for (int j = 0; j < 8; ++j) pp[j] += __shfl_xor(pp[j], d);
#pragma unroll
        for (int j = 0; j < 8; ++j) if (j >= cnt) pp[j] = -INFINITY;
        float mx = m;
#pragma unroll
        for (int j = 0; j < 8; ++j) mx = fmaxf(mx, pp[j]);
        float sc = __expf(m - mx);
        float ww[8];
#pragma unroll
        for (int j = 0; j < 8; ++j) ww[j] = __expf(pp[j] - mx);
        l *= sc;
        acc.x *= sc; acc.y *= sc; acc.z *= sc; acc.w *= sc;
#pragma unroll
        for (int j = 0; j < 8; ++j) {
            l += ww[j];
            acc.x += ww[j] * rr[j].x;
            acc.y += ww[j] * rr[j].y;
            acc.z += ww[j] * rr[j].z;
            acc.w += ww[j] * rr[j].w;
        }
        m = mx;
    }
    float inv = 1.f / (l + 1e-16f);
    float4 b4 = ((const float4*)bias)[lane];
    float4 o;
    o.x = elu(acc.x * inv + b4.x);
    o.y = elu(acc.y * inv + b4.y);
    o.z = elu(acc.z * inv + b4.z);
    o.w = elu(acc.w * inv + b4.w);
    stbf4(hout + (size_t)i * CH, lane, o);
}

// ---------------- Fused GATv2 layer 2 (bf16 in, fp32 out), 8-edge batched ----------------
__global__ void fused_gat2(const unsigned short* __restrict__ xl, const unsigned short* __restrict__ xr,
                           const int* __restrict__ rowptr, const int* __restrict__ csr,
                           const float* __restrict__ att, const float* __restrict__ bias,
                           float* __restrict__ out, int n) {
    int wid = threadIdx.x >> 6;
    int lane = threadIdx.x & 63;
    int i = blockIdx.x * 4 + wid;
    if (i >= n) return;
    float4 xr4 = ldbf4(xr + (size_t)i * CH, lane);
    float4 a4  = ((const float4*)att)[lane];
    float4 xli = ldbf4(xl + (size_t)i * CH, lane);
    float ps = lrelu(xli.x + xr4.x) * a4.x + lrelu(xli.y + xr4.y) * a4.y +
               lrelu(xli.z + xr4.z) * a4.z + lrelu(xli.w + xr4.w) * a4.w;
    ps += __shfl_xor(ps, 1); ps += __shfl_xor(ps, 2); ps += __shfl_xor(ps, 4);
    ps += __shfl_xor(ps, 8); ps += __shfl_xor(ps, 16); ps += __shfl_xor(ps, 32);
    float m = ps, l = 1.f;
    float4 acc = xli;
    int beg = rowptr[i], end = rowptr[i + 1];
    for (int e = beg; e < end; e += 8) {
        int cnt = end - e;
        int ss[8];
#pragma unroll
        for (int j = 0; j < 8; ++j) ss[j] = (j < cnt) ? csr[e + j] : i;
        float4 rr[8];
#pragma unroll
        for (int j = 0; j < 8; ++j) rr[j] = ldbf4(xl + (size_t)ss[j] * CH, lane);
        float pp[8];
#pragma unroll
        for (int j = 0; j < 8; ++j)
            pp[j] = lrelu(rr[j].x + xr4.x) * a4.x + lrelu(rr[j].y + xr4.y) * a4.y +
                    lrelu(rr[j].z + xr4.z) * a4.z + lrelu(rr[j].w + xr4.w) * a4.w;
#pragma unroll
        for (int d = 1; d < 64; d <<= 1)
#pragma unroll
            for (int j = 0; j < 8; ++j) pp[j] += __shfl_xor(pp[j], d);
#pragma unroll
        for (int j = 0; j < 8; ++j) if (j >= cnt) pp[j] = -INFINITY;
        float mx = m;
#pragma unroll
        for (int j = 0; j < 8; ++j) mx = fmaxf(mx, pp[j]);
        float sc = __expf(m - mx);
        float ww[8];
#pragma unroll
        for (int j = 0; j < 8; ++j) ww[j] = __expf(pp[j] - mx);
        l *= sc;
        acc.x *= sc; acc.y *= sc; acc.z *= sc; acc.w *= sc;
#pragma unroll
        for (int j = 0; j < 8; ++j) {
            l += ww[j];
            acc.x += ww[j] * rr[j].x;
            acc.y += ww[j] * rr[j].y;
            acc.z += ww[j] * rr[j].z;
            acc.w += ww[j] * rr[j].w;
        }
        m = mx;
    }
    float inv = 1.f / (l + 1e-16f);
    float4 b4 = ((const float4*)bias)[lane];
    float4 o;
    o.x = acc.x * inv + b4.x;
    o.y = acc.y * inv + b4.y;
    o.z = acc.z * inv + b4.z;
    o.w = acc.w * inv + b4.w;
    ((float4*)(out + (size_t)i * CH))[lane] = o;
}

// ---------------- transpose+convert layer2 weights: Wt[z][n][k] bf16 ----------------
__global__ void wconv(const float* __restrict__ Wl2, const float* __restrict__ Wr2,
                      unsigned short* __restrict__ Wt) {
    int t = blockIdx.x * 256 + threadIdx.x;
    int z = t >> 16;
    int idx = t & 65535;
    int k = idx >> 8, nn = idx & 255;
    const float* W = z ? Wr2 : Wl2;
    Wt[z * 65536 + nn * 256 + k] = f2bf(W[k * 256 + nn]);
}

// ---------------- GEMM2 MFMA: h (M x 256 bf16) @ Wt^T + b -> bf16 ----------------
// A staged in LDS in 2 half-K stages (3 barriers/block); B streamed from L2-hot
// weights straight to registers with 1-iter prefetch; (z,y) in grid LSBs for
// A-tile cache reuse.
#define LDA 132
__global__ __launch_bounds__(256) void gemm_mfma(
        const unsigned short* __restrict__ A,
        const unsigned short* __restrict__ Wt,
        const float* __restrict__ ba, const float* __restrict__ bb,
        unsigned short* __restrict__ Ca, unsigned short* __restrict__ Cb, int M) {
    int b = blockIdx.x;
    int z = b & 1, y = (b >> 1) & 1, xb = b >> 2;
    const unsigned short* Wz = Wt + (size_t)z * 65536;
    const float* bias = z ? bb : ba;
    unsigned short* C = z ? Cb : Ca;
    int m0 = xb * 128, n0 = y * 128;

    __shared__ unsigned short As[128 * LDA];

    int tid = threadIdx.x, lane = tid & 63, wid = tid >> 6;
    int wm = wid & 1, wn = wid >> 1, q = lane >> 4, l15 = lane & 15;

    f32x4 acc[4][4];
#pragma unroll
    for (int i = 0; i < 4; ++i)
#pragma unroll
        for (int j = 0; j < 4; ++j) acc[i][j] = (f32x4){0.f, 0.f, 0.f, 0.f};

    int srow = tid >> 1, shalf = tid & 1;
    bool rowok = (m0 + srow) < M;
    const unsigned short* gA = A + (size_t)(m0 + srow) * 256 + shalf * 64;
    unsigned short* sA = As + srow * LDA + shalf * 64;
    const uint4 z4 = make_uint4(0, 0, 0, 0);

    uint4 st[8];
#pragma unroll
    for (int i = 0; i < 8; ++i)
        st[i] = rowok ? *(const uint4*)(gA + i * 8) : z4;

    const unsigned short* gB = Wz + (size_t)(n0 + wn * 64 + l15) * 256 + q * 8;
    bf16x8 bc[4], bn[4];
#pragma unroll
    for (int j = 0; j < 4; ++j)
        bc[j] = *(const bf16x8*)(gB + j * 4096);

#pragma unroll
    for (int i = 0; i < 8; ++i)
        *(uint4*)(sA + i * 8) = st[i];
    __syncthreads();

#pragma unroll
    for (int kb = 0; kb < 8; ++kb) {
        if (kb == 1) {  // issue stage-1 A loads (K = 128..255), needed at kb==3 end
#pragma unroll
            for (int i = 0; i < 8; ++i)
                st[i] = rowok ? *(const uint4*)(gA + 128 + i * 8) : z4;
        }
        if (kb < 7) {   // prefetch next B fragments
#pragma unroll
            for (int j = 0; j < 4; ++j)
                bn[j] = *(const bf16x8*)(gB + j * 4096 + (kb + 1) * 32);
        }
        bf16x8 af[4];
#pragma unroll
        for (int i = 0; i < 4; ++i)
            af[i] = *(const bf16x8*)&As[(wm * 64 + i * 16 + l15) * LDA + (kb & 3) * 32 + q * 8];
#pragma unroll
        for (int i = 0; i < 4; ++i)
#pragma unroll
            for (int j = 0; j < 4; ++j)
                acc[i][j] = __builtin_amdgcn_mfma_f32_16x16x32_bf16(af[i], bc[j], acc[i][j], 0, 0, 0);
        if (kb < 7) {
#pragma unroll
            for (int j = 0; j < 4; ++j) bc[j] = bn[j];
        }
        if (kb == 3) {  // swap to stage 1
            __syncthreads();
#pragma unroll
            for (int i = 0; i < 8; ++i)
                *(uint4*)(sA + i * 8) = st[i];
            __syncthreads();
        }
    }

#pragma unroll
    for (int j = 0; j < 4; ++j) {
        int gcol = n0 + wn * 64 + j * 16 + l15;
        float bcol = bias[gcol];
#pragma unroll
        for (int i = 0; i < 4; ++i) {
            int row = m0 + wm * 64 + i * 16 + q * 4;
#pragma unroll
            for (int rr = 0; rr < 4; ++rr) {
                int grow = row + rr;
                if (grow < M)
                    C[(size_t)grow * 256 + gcol] = f2bf(acc[i][j][rr] + bcol);
            }
        }
    }
}

extern "C" void kernel_launch(void* const* d_in, const int* in_sizes, int n_in,
                              void* d_out, int out_size, void* d_ws, size_t ws_size,
                              hipStream_t stream) {
    const float* x    = (const float*)d_in[0];
    const int*   ei   = (const int*)d_in[1];
    const float* Wl1  = (const float*)d_in[2];
    const float* bl1  = (const float*)d_in[3];
    const float* Wr1  = (const float*)d_in[4];
    const float* br1  = (const float*)d_in[5];
    const float* att1 = (const float*)d_in[6];
    const float* bias1= (const float*)d_in[7];
    const float* Wl2  = (const float*)d_in[8];
    const float* bl2  = (const float*)d_in[9];
    const float* Wr2  = (const float*)d_in[10];
    const float* br2  = (const float*)d_in[11];
    const float* att2 = (const float*)d_in[12];
    const float* bias2= (const float*)d_in[13];

    int n = in_sizes[0] / 20;
    int e = in_sizes[1] / 2;
    float* out = (float*)d_out;
    size_t nch = (size_t)n * CH;

    unsigned short* buf0 = (unsigned short*)d_ws;
    unsigned short* buf1 = buf0 + nch;
    unsigned short* hbuf = buf1 + nch;
    unsigned short* wt2  = hbuf + nch;
    int* deg    = (int*)(wt2 + 2 * 65536);
    int* rowptr = deg + n;
    int* cursor = rowptr + n + 1;
    int* bsums  = cursor + n;
    int* csr    = bsums + 64;

    hipMemsetAsync(deg, 0, (size_t)n * sizeof(int), stream);

    gemm1_kernel<<<(n + 63) / 64, 256, 0, stream>>>(x, Wl1, bl1, Wr1, br1, buf0, buf1, n);

    count_deg<<<(e + 255) / 256, 256, 0, stream>>>(ei, deg, e);
    int nb = (n + SCAN_BLOCK - 1) / SCAN_BLOCK;
    scan_block_k<<<nb, SCAN_BLOCK, 0, stream>>>(deg, rowptr, bsums, n);
    scan_tops_k<<<1, 64, 0, stream>>>(bsums, nb);
    scan_fix_k<<<nb, SCAN_BLOCK, 0, stream>>>(rowptr, cursor, deg, bsums, n);
    scatter_k<<<(e + 255) / 256, 256, 0, stream>>>(ei, cursor, csr, e);

    wconv<<<512, 256, 0, stream>>>(Wl2, Wr2, wt2);

    fused_gat1<<<(n + 3) / 4, 256, 0, stream>>>(buf0, buf1, rowptr, csr, att1, bias1, hbuf, n);

    gemm_mfma<<<((n + 127) / 128) * 4, 256, 0, stream>>>(hbuf, wt2, bl2, br2, buf0, buf1, n);

    fused_gat2<<<(n + 3) / 4, 256, 0, stream>>>(buf0, buf1, rowptr, csr, att2, bias2, out, n);
}

// Round 5
// 366.869 us; speedup vs baseline: 1.0651x; 1.0651x over previous
//
#include <hip/hip_runtime.h>
#include <hip/hip_bf16.h>
#include <math.h>

#define CH 256
#define SCAN_BLOCK 1024

typedef short bf16x8 __attribute__((ext_vector_type(8)));
typedef float f32x4 __attribute__((ext_vector_type(4)));

__device__ __forceinline__ float lrelu(float v) { return fmaxf(v, 0.2f * v); }
__device__ __forceinline__ float elu(float v)   { return v > 0.f ? v : __expf(v) - 1.f; }

__device__ __forceinline__ unsigned short f2bf(float f) {
    unsigned u = __float_as_uint(f);
    return (unsigned short)((u + 0x7fffu + ((u >> 16) & 1u)) >> 16);
}
__device__ __forceinline__ float4 ldbf4(const unsigned short* rowbase, int lane) {
    uint2 u = ((const uint2*)rowbase)[lane];
    return make_float4(__uint_as_float(u.x << 16), __uint_as_float(u.x & 0xffff0000u),
                       __uint_as_float(u.y << 16), __uint_as_float(u.y & 0xffff0000u));
}
__device__ __forceinline__ void stbf4(unsigned short* rowbase, int lane, float4 v) {
    uint2 u;
    u.x = (unsigned)f2bf(v.x) | ((unsigned)f2bf(v.y) << 16);
    u.y = (unsigned)f2bf(v.z) | ((unsigned)f2bf(v.w) << 16);
    ((uint2*)rowbase)[lane] = u;
}

// ---------------- GEMM1: x (n x 20) @ W (20 x 256) + b -> bf16 xl, xr ----------------
__global__ __launch_bounds__(256) void gemm1_kernel(const float* __restrict__ x,
                             const float* __restrict__ Wl, const float* __restrict__ bl,
                             const float* __restrict__ Wr, const float* __restrict__ br,
                             unsigned short* __restrict__ xl, unsigned short* __restrict__ xr, int n) {
    __shared__ float xs[64][20];
    int n0 = blockIdx.x * 64;
    int tid = threadIdx.x;
    for (int i = tid; i < 64 * 20; i += 256) {
        int m = i / 20, k = i % 20;
        int row = n0 + m;
        xs[m][k] = (row < n) ? x[(size_t)row * 20 + k] : 0.f;
    }
    int c = tid;
    float wl[20], wr[20];
#pragma unroll
    for (int k = 0; k < 20; ++k) { wl[k] = Wl[k * 256 + c]; wr[k] = Wr[k * 256 + c]; }
    float blv = bl[c], brv = br[c];
    __syncthreads();
#pragma unroll 1
    for (int g = 0; g < 8; ++g) {
        int base = g * 8;
        float al[8], ar[8];
#pragma unroll
        for (int m = 0; m < 8; ++m) { al[m] = blv; ar[m] = brv; }
#pragma unroll
        for (int k = 0; k < 20; ++k) {
            float wlv = wl[k], wrv = wr[k];
#pragma unroll
            for (int m = 0; m < 8; ++m) {
                float xv = xs[base + m][k];
                al[m] += xv * wlv;
                ar[m] += xv * wrv;
            }
        }
#pragma unroll
        for (int m = 0; m < 8; ++m) {
            int row = n0 + base + m;
            if (row < n) {
                xl[(size_t)row * 256 + c] = f2bf(al[m]);
                xr[(size_t)row * 256 + c] = f2bf(ar[m]);
            }
        }
    }
}

// ---------------- CSR build ----------------
__global__ void count_deg(const int* __restrict__ ei, int* __restrict__ deg, int e) {
    int t = blockIdx.x * blockDim.x + threadIdx.x;
    if (t < e) atomicAdd(&deg[ei[e + t]], 1);
}

__global__ void scan_block_k(const int* __restrict__ deg, int* __restrict__ rowptr,
                             int* __restrict__ bsums, int n) {
    __shared__ int wsum[16];
    __shared__ int woff[17];
    int tid = threadIdx.x;
    int gi = blockIdx.x * SCAN_BLOCK + tid;
    int lane = tid & 63, wid = tid >> 6;
    int v = (gi < n) ? deg[gi] : 0;
    int incl = v;
#pragma unroll
    for (int d = 1; d < 64; d <<= 1) {
        int t = __shfl_up(incl, d, 64);
        if (lane >= d) incl += t;
    }
    if (lane == 63) wsum[wid] = incl;
    __syncthreads();
    if (tid < 16) {
        int s = wsum[tid];
#pragma unroll
        for (int d = 1; d < 16; d <<= 1) {
            int t = __shfl_up(s, d, 64);
            if (tid >= d) s += t;
        }
        woff[tid + 1] = s;
        if (tid == 0) woff[0] = 0;
    }
    __syncthreads();
    incl += woff[wid];
    if (gi < n) rowptr[gi + 1] = incl;
    if (tid == 0) bsums[blockIdx.x] = woff[16];
}

__global__ void scan_tops_k(int* bsums, int nb) {
    int tid = threadIdx.x;
    int v = (tid < nb) ? bsums[tid] : 0;
    int incl = v;
#pragma unroll
    for (int d = 1; d < 64; d <<= 1) {
        int t = __shfl_up(incl, d, 64);
        if (tid >= d) incl += t;
    }
    if (tid < nb) bsums[tid] = incl - v;
}

__global__ void scan_fix_k(int* __restrict__ rowptr, int* __restrict__ cursor,
                           const int* __restrict__ deg, const int* __restrict__ bsums, int n) {
    int gi = blockIdx.x * SCAN_BLOCK + threadIdx.x;
    if (gi >= n) return;
    int off = bsums[blockIdx.x];
    int incl = rowptr[gi + 1] + off;
    rowptr[gi + 1] = incl;
    cursor[gi] = incl - deg[gi];
    if (gi == 0) rowptr[0] = 0;
}

__global__ void scatter_k(const int* __restrict__ ei, int* __restrict__ cursor,
                          int* __restrict__ csr, int e) {
    int t = blockIdx.x * blockDim.x + threadIdx.x;
    if (t >= e) return;
    int s = ei[t], d = ei[e + t];
    int idx = atomicAdd(&cursor[d], 1);
    csr[idx] = s;
}

// ---------------- Fused GATv2 layer 1 (bf16 in, bf16 out), 8-edge batched ----------------
__global__ void fused_gat1(const unsigned short* __restrict__ xl, const unsigned short* __restrict__ xr,
                           const int* __restrict__ rowptr, const int* __restrict__ csr,
                           const float* __restrict__ att, const float* __restrict__ bias,
                           unsigned short* __restrict__ hout, int n) {
    int wid = threadIdx.x >> 6;
    int lane = threadIdx.x & 63;
    int i = blockIdx.x * 4 + wid;
    if (i >= n) return;
    float4 xr4 = ldbf4(xr + (size_t)i * CH, lane);
    float4 a4  = ((const float4*)att)[lane];
    float4 xli = ldbf4(xl + (size_t)i * CH, lane);
    float ps = lrelu(xli.x + xr4.x) * a4.x + lrelu(xli.y + xr4.y) * a4.y +
               lrelu(xli.z + xr4.z) * a4.z + lrelu(xli.w + xr4.w) * a4.w;
    ps += __shfl_xor(ps, 1); ps += __shfl_xor(ps, 2);
    ps += __shfl_xor(ps, 4); ps += __shfl_xor(ps, 8);
    float m = ps, l = 1.f;
    float4 acc = xli;
    int beg = rowptr[i], end = rowptr[i + 1];
    for (int e = beg; e < end; e += 8) {
        int cnt = end - e;
        int ss[8];
#pragma unroll
        for (int j = 0; j < 8; ++j) ss[j] = (j < cnt) ? csr[e + j] : i;
        float4 rr[8];
#pragma unroll
        for (int j = 0; j < 8; ++j) rr[j] = ldbf4(xl + (size_t)ss[j] * CH, lane);
        float pp[8];
#pragma unroll
        for (int j = 0; j < 8; ++j)
            pp[j] = lrelu(rr[j].x + xr4.x) * a4.x + lrelu(rr[j].y + xr4.y) * a4.y +
                    lrelu(rr[j].z + xr4.z) * a4.z + lrelu(rr[j].w + xr4.w) * a4.w;
#pragma unroll
        for (int d = 1; d < 16; d <<= 1)
#pragma unroll
            for (int j = 0; j < 8; ++j) pp[j] += __shfl_xor(pp[j], d);
#pragma unroll
        for (int j = 0; j < 8; ++j) if (j >= cnt) pp[j] = -INFINITY;
        float mx = m;
#pragma unroll
        for (int j = 0; j < 8; ++j) mx = fmaxf(mx, pp[j]);
        float sc = __expf(m - mx);
        float ww[8];
#pragma unroll
        for (int j = 0; j < 8; ++j) ww[j] = __expf(pp[j] - mx);
        l *= sc;
        acc.x *= sc; acc.y *= sc; acc.z *= sc; acc.w *= sc;
#pragma unroll
        for (int j = 0; j < 8; ++j) {
            l += ww[j];
            acc.x += ww[j] * rr[j].x;
            acc.y += ww[j] * rr[j].y;
            acc.z += ww[j] * rr[j].z;
            acc.w += ww[j] * rr[j].w;
        }
        m = mx;
    }
    float inv = 1.f / (l + 1e-16f);
    float4 b4 = ((const float4*)bias)[lane];
    float4 o;
    o.x = elu(acc.x * inv + b4.x);
    o.y = elu(acc.y * inv + b4.y);
    o.z = elu(acc.z * inv + b4.z);
    o.w = elu(acc.w * inv + b4.w);
    stbf4(hout + (size_t)i * CH, lane, o);
}

// ---------------- Fused GATv2 layer 2 (bf16 in, fp32 out), 8-edge batched ----------------
__global__ void fused_gat2(const unsigned short* __restrict__ xl, const unsigned short* __restrict__ xr,
                           const int* __restrict__ rowptr, const int* __restrict__ csr,
                           const float* __restrict__ att, const float* __restrict__ bias,
                           float* __restrict__ out, int n) {
    int wid = threadIdx.x >> 6;
    int lane = threadIdx.x & 63;
    int i = blockIdx.x * 4 + wid;
    if (i >= n) return;
    float4 xr4 = ldbf4(xr + (size_t)i * CH, lane);
    float4 a4  = ((const float4*)att)[lane];
    float4 xli = ldbf4(xl + (size_t)i * CH, lane);
    float ps = lrelu(xli.x + xr4.x) * a4.x + lrelu(xli.y + xr4.y) * a4.y +
               lrelu(xli.z + xr4.z) * a4.z + lrelu(xli.w + xr4.w) * a4.w;
    ps += __shfl_xor(ps, 1); ps += __shfl_xor(ps, 2); ps += __shfl_xor(ps, 4);
    ps += __shfl_xor(ps, 8); ps += __shfl_xor(ps, 16); ps += __shfl_xor(ps, 32);
    float m = ps, l = 1.f;
    float4 acc = xli;
    int beg = rowptr[i], end = rowptr[i + 1];
    for (int e = beg; e < end; e += 8) {
        int cnt = end - e;
        int ss[8];
#pragma unroll
        for (int j = 0; j < 8; ++j) ss[j] = (j < cnt) ? csr[e + j] : i;
        float4 rr[8];
#pragma unroll
        for (int j = 0; j < 8; ++j) rr[j] = ldbf4(xl + (size_t)ss[j] * CH, lane);
        float pp[8];
#pragma unroll
        for (int j = 0; j < 8; ++j)
            pp[j] = lrelu(rr[j].x + xr4.x) * a4.x + lrelu(rr[j].y + xr4.y) * a4.y +
                    lrelu(rr[j].z + xr4.z) * a4.z + lrelu(rr[j].w + xr4.w) * a4.w;
#pragma unroll
        for (int d = 1; d < 64; d <<= 1)
#pragma unroll
            for (int j = 0; j < 8; ++j) pp[j] += __shfl_xor(pp[j], d);
#pragma unroll
        for (int j = 0; j < 8; ++j) if (j >= cnt) pp[j] = -INFINITY;
        float mx = m;
#pragma unroll
        for (int j = 0; j < 8; ++j) mx = fmaxf(mx, pp[j]);
        float sc = __expf(m - mx);
        float ww[8];
#pragma unroll
        for (int j = 0; j < 8; ++j) ww[j] = __expf(pp[j] - mx);
        l *= sc;
        acc.x *= sc; acc.y *= sc; acc.z *= sc; acc.w *= sc;
#pragma unroll
        for (int j = 0; j < 8; ++j) {
            l += ww[j];
            acc.x += ww[j] * rr[j].x;
            acc.y += ww[j] * rr[j].y;
            acc.z += ww[j] * rr[j].z;
            acc.w += ww[j] * rr[j].w;
        }
        m = mx;
    }
    float inv = 1.f / (l + 1e-16f);
    float4 b4 = ((const float4*)bias)[lane];
    float4 o;
    o.x = acc.x * inv + b4.x;
    o.y = acc.y * inv + b4.y;
    o.z = acc.z * inv + b4.z;
    o.w = acc.w * inv + b4.w;
    ((float4*)(out + (size_t)i * CH))[lane] = o;
}

// ---------------- transpose+convert layer2 weights: Wt[z][n][k] bf16 ----------------
__global__ void wconv(const float* __restrict__ Wl2, const float* __restrict__ Wr2,
                      unsigned short* __restrict__ Wt) {
    int t = blockIdx.x * 256 + threadIdx.x;
    int z = t >> 16;
    int idx = t & 65535;
    int k = idx >> 8, nn = idx & 255;
    const float* W = z ? Wr2 : Wl2;
    Wt[z * 65536 + nn * 256 + k] = f2bf(W[k * 256 + nn]);
}

// ---------------- GEMM2 MFMA: h (M x 256 bf16) @ Wt^T + b -> bf16 ----------------
// Low-register design: B strip staged in LDS in 2 half-K stages (3 barriers);
// A fragments loaded lane-direct from global (L2-hot) with 1-iter prefetch;
// coalesced epilogue via LDS tile reuse.
#define LDB 136
__global__ __launch_bounds__(256) void gemm_mfma(
        const unsigned short* __restrict__ A,
        const unsigned short* __restrict__ Wt,
        const float* __restrict__ ba, const float* __restrict__ bb,
        unsigned short* __restrict__ Ca, unsigned short* __restrict__ Cb, int M) {
    int b = blockIdx.x;
    int z = b & 1, y = (b >> 1) & 1, xb = b >> 2;
    const unsigned short* Wz = Wt + (size_t)z * 65536 + (size_t)y * 32768; // 128-row n-strip
    const float* bias = z ? bb : ba;
    unsigned short* C = z ? Cb : Ca;
    int m0 = xb * 128, n0 = y * 128;

    __shared__ unsigned short Bs[128 * LDB];

    int tid = threadIdx.x, lane = tid & 63, wid = tid >> 6;
    int wm = wid & 1, wn = wid >> 1, q = lane >> 4, l15 = lane & 15;

    f32x4 acc[4][4];
#pragma unroll
    for (int i = 0; i < 4; ++i)
#pragma unroll
        for (int j = 0; j < 4; ++j) acc[i][j] = (f32x4){0.f, 0.f, 0.f, 0.f};

    // A fragment pointers (row-clamped; clamped rows' results are discarded)
    const unsigned short* pA[4];
#pragma unroll
    for (int i = 0; i < 4; ++i) {
        int row = m0 + wm * 64 + i * 16 + l15;
        row = row < M ? row : M - 1;
        pA[i] = A + (size_t)row * 256 + q * 8;
    }

    // stage 0 of B: k in [0,128)
    uint4 tmp[8];
#pragma unroll
    for (int i = 0; i < 8; ++i) {
        int c = i * 256 + tid;                      // 2048 chunks of 16B
        tmp[i] = *(const uint4*)(Wz + (c >> 4) * 256 + (c & 15) * 8);
    }
    bf16x8 a_cur[4], a_nxt[4];
#pragma unroll
    for (int i = 0; i < 4; ++i) a_cur[i] = *(const bf16x8*)pA[i];
#pragma unroll
    for (int i = 0; i < 8; ++i) {
        int c = i * 256 + tid;
        *(uint4*)(Bs + (c >> 4) * LDB + (c & 15) * 8) = tmp[i];
    }
    __syncthreads();

#pragma unroll
    for (int kb = 0; kb < 8; ++kb) {
        if (kb == 2) {  // fetch stage-1 B (k in [128,256)) ahead of the kb==3 swap
#pragma unroll
            for (int i = 0; i < 8; ++i) {
                int c = i * 256 + tid;
                tmp[i] = *(const uint4*)(Wz + (c >> 4) * 256 + 128 + (c & 15) * 8);
            }
        }
        if (kb < 7) {
#pragma unroll
            for (int i = 0; i < 4; ++i)
                a_nxt[i] = *(const bf16x8*)(pA[i] + (kb + 1) * 32);
        }
        bf16x8 bfr[4];
        int ks = (kb & 3) * 32;
#pragma unroll
        for (int j = 0; j < 4; ++j)
            bfr[j] = *(const bf16x8*)&Bs[(wn * 64 + j * 16 + l15) * LDB + ks + q * 8];
#pragma unroll
        for (int i = 0; i < 4; ++i)
#pragma unroll
            for (int j = 0; j < 4; ++j)
                acc[i][j] = __builtin_amdgcn_mfma_f32_16x16x32_bf16(a_cur[i], bfr[j], acc[i][j], 0, 0, 0);
        if (kb < 7) {
#pragma unroll
            for (int i = 0; i < 4; ++i) a_cur[i] = a_nxt[i];
        }
        if (kb == 3) {
            __syncthreads();
#pragma unroll
            for (int i = 0; i < 8; ++i) {
                int c = i * 256 + tid;
                *(uint4*)(Bs + (c >> 4) * LDB + (c & 15) * 8) = tmp[i];
            }
            __syncthreads();
        }
    }

    // epilogue: acc -> LDS tile (reuse Bs) -> coalesced global stores
    __syncthreads();
#pragma unroll
    for (int j = 0; j < 4; ++j) {
        int tcol = wn * 64 + j * 16 + l15;
        float bcol = bias[n0 + tcol];
#pragma unroll
        for (int i = 0; i < 4; ++i) {
            int trow = wm * 64 + i * 16 + q * 4;
#pragma unroll
            for (int rr = 0; rr < 4; ++rr)
                Bs[(trow + rr) * LDB + tcol] = f2bf(acc[i][j][rr] + bcol);
        }
    }
    __syncthreads();
    int row = tid >> 1, half = tid & 1;
    int grow = m0 + row;
    if (grow < M) {
        const uint4* src = (const uint4*)(Bs + row * LDB + half * 64);
        uint4* dst = (uint4*)(C + (size_t)grow * 256 + n0 + half * 64);
#pragma unroll
        for (int i = 0; i < 8; ++i) dst[i] = src[i];
    }
}

extern "C" void kernel_launch(void* const* d_in, const int* in_sizes, int n_in,
                              void* d_out, int out_size, void* d_ws, size_t ws_size,
                              hipStream_t stream) {
    const float* x    = (const float*)d_in[0];
    const int*   ei   = (const int*)d_in[1];
    const float* Wl1  = (const float*)d_in[2];
    const float* bl1  = (const float*)d_in[3];
    const float* Wr1  = (const float*)d_in[4];
    const float* br1  = (const float*)d_in[5];
    const float* att1 = (const float*)d_in[6];
    const float* bias1= (const float*)d_in[7];
    const float* Wl2  = (const float*)d_in[8];
    const float* bl2  = (const float*)d_in[9];
    const float* Wr2  = (const float*)d_in[10];
    const float* br2  = (const float*)d_in[11];
    const float* att2 = (const float*)d_in[12];
    const float* bias2= (const float*)d_in[13];

    int n = in_sizes[0] / 20;
    int e = in_sizes[1] / 2;
    float* out = (float*)d_out;
    size_t nch = (size_t)n * CH;

    unsigned short* buf0 = (unsigned short*)d_ws;
    unsigned short* buf1 = buf0 + nch;
    unsigned short* hbuf = buf1 + nch;
    unsigned short* wt2  = hbuf + nch;
    int* deg    = (int*)(wt2 + 2 * 65536);
    int* rowptr = deg + n;
    int* cursor = rowptr + n + 1;
    int* bsums  = cursor + n;
    int* csr    = bsums + 64;

    hipMemsetAsync(deg, 0, (size_t)n * sizeof(int), stream);

    gemm1_kernel<<<(n + 63) / 64, 256, 0, stream>>>(x, Wl1, bl1, Wr1, br1, buf0, buf1, n);

    count_deg<<<(e + 255) / 256, 256, 0, stream>>>(ei, deg, e);
    int nb = (n + SCAN_BLOCK - 1) / SCAN_BLOCK;
    scan_block_k<<<nb, SCAN_BLOCK, 0, stream>>>(deg, rowptr, bsums, n);
    scan_tops_k<<<1, 64, 0, stream>>>(bsums, nb);
    scan_fix_k<<<nb, SCAN_BLOCK, 0, stream>>>(rowptr, cursor, deg, bsums, n);
    scatter_k<<<(e + 255) / 256, 256, 0, stream>>>(ei, cursor, csr, e);

    wconv<<<512, 256, 0, stream>>>(Wl2, Wr2, wt2);

    fused_gat1<<<(n + 3) / 4, 256, 0, stream>>>(buf0, buf1, rowptr, csr, att1, bias1, hbuf, n);

    gemm_mfma<<<((n + 127) / 128) * 4, 256, 0, stream>>>(hbuf, wt2, bl2, br2, buf0, buf1, n);

    fused_gat2<<<(n + 3) / 4, 256, 0, stream>>>(buf0, buf1, rowptr, csr, att2, bias2, out, n);
}

// Round 7
// 340.465 us; speedup vs baseline: 1.1477x; 1.0775x over previous
//
#include <hip/hip_runtime.h>
#include <hip/hip_bf16.h>
#include <math.h>

#define CH 256
#define SCAN_BLOCK 1024

typedef short bf16x8 __attribute__((ext_vector_type(8)));
typedef float f32x4 __attribute__((ext_vector_type(4)));

__device__ __forceinline__ float lrelu(float v) { return fmaxf(v, 0.2f * v); }
__device__ __forceinline__ float elu(float v)   { return v > 0.f ? v : __expf(v) - 1.f; }

__device__ __forceinline__ unsigned short f2bf(float f) {
    unsigned u = __float_as_uint(f);
    return (unsigned short)((u + 0x7fffu + ((u >> 16) & 1u)) >> 16);
}
__device__ __forceinline__ float4 ldbf4(const unsigned short* rowbase, int lane) {
    uint2 u = ((const uint2*)rowbase)[lane];
    return make_float4(__uint_as_float(u.x << 16), __uint_as_float(u.x & 0xffff0000u),
                       __uint_as_float(u.y << 16), __uint_as_float(u.y & 0xffff0000u));
}
__device__ __forceinline__ void stbf4(unsigned short* rowbase, int lane, float4 v) {
    uint2 u;
    u.x = (unsigned)f2bf(v.x) | ((unsigned)f2bf(v.y) << 16);
    u.y = (unsigned)f2bf(v.z) | ((unsigned)f2bf(v.w) << 16);
    ((uint2*)rowbase)[lane] = u;
}

// ---------------- GEMM1: x (n x 20) @ W (20 x 256) + b -> bf16 xl, xr ----------------
__global__ __launch_bounds__(256) void gemm1_kernel(const float* __restrict__ x,
                             const float* __restrict__ Wl, const float* __restrict__ bl,
                             const float* __restrict__ Wr, const float* __restrict__ br,
                             unsigned short* __restrict__ xl, unsigned short* __restrict__ xr, int n) {
    __shared__ float xs[64][20];
    int n0 = blockIdx.x * 64;
    int tid = threadIdx.x;
    for (int i = tid; i < 64 * 20; i += 256) {
        int m = i / 20, k = i % 20;
        int row = n0 + m;
        xs[m][k] = (row < n) ? x[(size_t)row * 20 + k] : 0.f;
    }
    int c = tid;
    float wl[20], wr[20];
#pragma unroll
    for (int k = 0; k < 20; ++k) { wl[k] = Wl[k * 256 + c]; wr[k] = Wr[k * 256 + c]; }
    float blv = bl[c], brv = br[c];
    __syncthreads();
#pragma unroll 1
    for (int g = 0; g < 8; ++g) {
        int base = g * 8;
        float al[8], ar[8];
#pragma unroll
        for (int m = 0; m < 8; ++m) { al[m] = blv; ar[m] = brv; }
#pragma unroll
        for (int k = 0; k < 20; ++k) {
            float wlv = wl[k], wrv = wr[k];
#pragma unroll
            for (int m = 0; m < 8; ++m) {
                float xv = xs[base + m][k];
                al[m] += xv * wlv;
                ar[m] += xv * wrv;
            }
        }
#pragma unroll
        for (int m = 0; m < 8; ++m) {
            int row = n0 + base + m;
            if (row < n) {
                xl[(size_t)row * 256 + c] = f2bf(al[m]);
                xr[(size_t)row * 256 + c] = f2bf(ar[m]);
            }
        }
    }
}

// ---------------- CSR build ----------------
__global__ void count_deg(const int* __restrict__ ei, int* __restrict__ deg, int e) {
    int t = blockIdx.x * blockDim.x + threadIdx.x;
    if (t < e) atomicAdd(&deg[ei[e + t]], 1);
}

__global__ void scan_block_k(const int* __restrict__ deg, int* __restrict__ rowptr,
                             int* __restrict__ bsums, int n) {
    __shared__ int wsum[16];
    __shared__ int woff[17];
    int tid = threadIdx.x;
    int gi = blockIdx.x * SCAN_BLOCK + tid;
    int lane = tid & 63, wid = tid >> 6;
    int v = (gi < n) ? deg[gi] : 0;
    int incl = v;
#pragma unroll
    for (int d = 1; d < 64; d <<= 1) {
        int t = __shfl_up(incl, d, 64);
        if (lane >= d) incl += t;
    }
    if (lane == 63) wsum[wid] = incl;
    __syncthreads();
    if (tid < 16) {
        int s = wsum[tid];
#pragma unroll
        for (int d = 1; d < 16; d <<= 1) {
            int t = __shfl_up(s, d, 64);
            if (tid >= d) s += t;
        }
        woff[tid + 1] = s;
        if (tid == 0) woff[0] = 0;
    }
    __syncthreads();
    incl += woff[wid];
    if (gi < n) rowptr[gi + 1] = incl;
    if (tid == 0) bsums[blockIdx.x] = woff[16];
}

__global__ void scan_tops_k(int* bsums, int nb) {
    int tid = threadIdx.x;
    int v = (tid < nb) ? bsums[tid] : 0;
    int incl = v;
#pragma unroll
    for (int d = 1; d < 64; d <<= 1) {
        int t = __shfl_up(incl, d, 64);
        if (tid >= d) incl += t;
    }
    if (tid < nb) bsums[tid] = incl - v;
}

__global__ void scan_fix_k(int* __restrict__ rowptr, int* __restrict__ cursor,
                           const int* __restrict__ deg, const int* __restrict__ bsums, int n) {
    int gi = blockIdx.x * SCAN_BLOCK + threadIdx.x;
    if (gi >= n) return;
    int off = bsums[blockIdx.x];
    int incl = rowptr[gi + 1] + off;
    rowptr[gi + 1] = incl;
    cursor[gi] = incl - deg[gi];
    if (gi == 0) rowptr[0] = 0;
}

__global__ void scatter_k(const int* __restrict__ ei, int* __restrict__ cursor,
                          int* __restrict__ csr, int e) {
    int t = blockIdx.x * blockDim.x + threadIdx.x;
    if (t >= e) return;
    int s = ei[t], d = ei[e + t];
    int idx = atomicAdd(&cursor[d], 1);
    csr[idx] = s;
}

// ---------------- Fused GATv2 layer 1 (bf16 in, bf16 out), 8-edge batched ----------------
__global__ void fused_gat1(const unsigned short* __restrict__ xl, const unsigned short* __restrict__ xr,
                           const int* __restrict__ rowptr, const int* __restrict__ csr,
                           const float* __restrict__ att, const float* __restrict__ bias,
                           unsigned short* __restrict__ hout, int n) {
    int wid = threadIdx.x >> 6;
    int lane = threadIdx.x & 63;
    int i = blockIdx.x * 4 + wid;
    if (i >= n) return;
    float4 xr4 = ldbf4(xr + (size_t)i * CH, lane);
    float4 a4  = ((const float4*)att)[lane];
    float4 xli = ldbf4(xl + (size_t)i * CH, lane);
    float ps = lrelu(xli.x + xr4.x) * a4.x + lrelu(xli.y + xr4.y) * a4.y +
               lrelu(xli.z + xr4.z) * a4.z + lrelu(xli.w + xr4.w) * a4.w;
    ps += __shfl_xor(ps, 1); ps += __shfl_xor(ps, 2);
    ps += __shfl_xor(ps, 4); ps += __shfl_xor(ps, 8);
    float m = ps, l = 1.f;
    float4 acc = xli;
    int beg = rowptr[i], end = rowptr[i + 1];
    for (int e = beg; e < end; e += 8) {
        int cnt = end - e;
        int ss[8];
#pragma unroll
        for (int j = 0; j < 8; ++j) ss[j] = (j < cnt) ? csr[e + j] : i;
        float4 rr[8];
#pragma unroll
        for (int j = 0; j < 8; ++j) rr[j] = ldbf4(xl + (size_t)ss[j] * CH, lane);
        float pp[8];
#pragma unroll
        for (int j = 0; j < 8; ++j)
            pp[j] = lrelu(rr[j].x + xr4.x) * a4.x + lrelu(rr[j].y + xr4.y) * a4.y +
                    lrelu(rr[j].z + xr4.z) * a4.z + lrelu(rr[j].w + xr4.w) * a4.w;
#pragma unroll
        for (int d = 1; d < 16; d <<= 1)
#pragma unroll
            for (int j = 0; j < 8; ++j) pp[j] += __shfl_xor(pp[j], d);
#pragma unroll
        for (int j = 0; j < 8; ++j) if (j >= cnt) pp[j] = -INFINITY;
        float mx = m;
#pragma unroll
        for (int j = 0; j < 8; ++j) mx = fmaxf(mx, pp[j]);
        float sc = __expf(m - mx);
        float ww[8];
#pragma unroll
        for (int j = 0; j < 8; ++j) ww[j] = __expf(pp[j] - mx);
        l *= sc;
        acc.x *= sc; acc.y *= sc; acc.z *= sc; acc.w *= sc;
#pragma unroll
        for (int j = 0; j < 8; ++j) {
            l += ww[j];
            acc.x += ww[j] * rr[j].x;
            acc.y += ww[j] * rr[j].y;
            acc.z += ww[j] * rr[j].z;
            acc.w += ww[j] * rr[j].w;
        }
        m = mx;
    }
    float inv = 1.f / (l + 1e-16f);
    float4 b4 = ((const float4*)bias)[lane];
    float4 o;
    o.x = elu(acc.x * inv + b4.x);
    o.y = elu(acc.y * inv + b4.y);
    o.z = elu(acc.z * inv + b4.z);
    o.w = elu(acc.w * inv + b4.w);
    stbf4(hout + (size_t)i * CH, lane, o);
}

// ---------------- Fused GATv2 layer 2 (bf16 in, fp32 out), 8-edge batched ----------------
__global__ void fused_gat2(const unsigned short* __restrict__ xl, const unsigned short* __restrict__ xr,
                           const int* __restrict__ rowptr, const int* __restrict__ csr,
                           const float* __restrict__ att, const float* __restrict__ bias,
                           float* __restrict__ out, int n) {
    int wid = threadIdx.x >> 6;
    int lane = threadIdx.x & 63;
    int i = blockIdx.x * 4 + wid;
    if (i >= n) return;
    float4 xr4 = ldbf4(xr + (size_t)i * CH, lane);
    float4 a4  = ((const float4*)att)[lane];
    float4 xli = ldbf4(xl + (size_t)i * CH, lane);
    float ps = lrelu(xli.x + xr4.x) * a4.x + lrelu(xli.y + xr4.y) * a4.y +
               lrelu(xli.z + xr4.z) * a4.z + lrelu(xli.w + xr4.w) * a4.w;
    ps += __shfl_xor(ps, 1); ps += __shfl_xor(ps, 2); ps += __shfl_xor(ps, 4);
    ps += __shfl_xor(ps, 8); ps += __shfl_xor(ps, 16); ps += __shfl_xor(ps, 32);
    float m = ps, l = 1.f;
    float4 acc = xli;
    int beg = rowptr[i], end = rowptr[i + 1];
    for (int e = beg; e < end; e += 8) {
        int cnt = end - e;
        int ss[8];
#pragma unroll
        for (int j = 0; j < 8; ++j) ss[j] = (j < cnt) ? csr[e + j] : i;
        float4 rr[8];
#pragma unroll
        for (int j = 0; j < 8; ++j) rr[j] = ldbf4(xl + (size_t)ss[j] * CH, lane);
        float pp[8];
#pragma unroll
        for (int j = 0; j < 8; ++j)
            pp[j] = lrelu(rr[j].x + xr4.x) * a4.x + lrelu(rr[j].y + xr4.y) * a4.y +
                    lrelu(rr[j].z + xr4.z) * a4.z + lrelu(rr[j].w + xr4.w) * a4.w;
#pragma unroll
        for (int d = 1; d < 64; d <<= 1)
#pragma unroll
            for (int j = 0; j < 8; ++j) pp[j] += __shfl_xor(pp[j], d);
#pragma unroll
        for (int j = 0; j < 8; ++j) if (j >= cnt) pp[j] = -INFINITY;
        float mx = m;
#pragma unroll
        for (int j = 0; j < 8; ++j) mx = fmaxf(mx, pp[j]);
        float sc = __expf(m - mx);
        float ww[8];
#pragma unroll
        for (int j = 0; j < 8; ++j) ww[j] = __expf(pp[j] - mx);
        l *= sc;
        acc.x *= sc; acc.y *= sc; acc.z *= sc; acc.w *= sc;
#pragma unroll
        for (int j = 0; j < 8; ++j) {
            l += ww[j];
            acc.x += ww[j] * rr[j].x;
            acc.y += ww[j] * rr[j].y;
            acc.z += ww[j] * rr[j].z;
            acc.w += ww[j] * rr[j].w;
        }
        m = mx;
    }
    float inv = 1.f / (l + 1e-16f);
    float4 b4 = ((const float4*)bias)[lane];
    float4 o;
    o.x = acc.x * inv + b4.x;
    o.y = acc.y * inv + b4.y;
    o.z = acc.z * inv + b4.z;
    o.w = acc.w * inv + b4.w;
    ((float4*)(out + (size_t)i * CH))[lane] = o;
}

// ---------------- transpose+convert layer2 weights: Wt[z][n][k] bf16 ----------------
__global__ void wconv(const float* __restrict__ Wl2, const float* __restrict__ Wr2,
                      unsigned short* __restrict__ Wt) {
    int t = blockIdx.x * 256 + threadIdx.x;
    int z = t >> 16;
    int idx = t & 65535;
    int k = idx >> 8, nn = idx & 255;
    const float* W = z ? Wr2 : Wl2;
    Wt[z * 65536 + nn * 256 + k] = f2bf(W[k * 256 + nn]);
}

// ---------------- GEMM2 MFMA v3 (store-width fixed) ----------------
// Block = 64 A-rows (LDS-resident, staged once, 1 barrier) x 128 n-cols (y half)
// x both z weight matrices. 16 barrier-free K-steps of 8 MFMA; B fragments
// register-prefetched 1 step ahead from the L2-hot 256 KB weight array.
#define LDA2 264
#define LDC2 136
__global__ __launch_bounds__(256) void gemm_mfma(
        const unsigned short* __restrict__ A,
        const unsigned short* __restrict__ Wt,   // [z][n][k] bf16
        const float* __restrict__ ba, const float* __restrict__ bb,
        unsigned short* __restrict__ Ca, unsigned short* __restrict__ Cb, int M) {
    int b = blockIdx.x;
    int y = b & 1, mt = b >> 1;
    int m0 = mt * 64, n0 = y * 128;

    __shared__ unsigned short As[64 * LDA2];
    __shared__ unsigned short Cs[64 * LDC2];

    int tid = threadIdx.x, lane = tid & 63, wn = tid >> 6;
    int q = lane >> 4, l15 = lane & 15;

    // ---- stage A tile (64 rows x 256 k) into LDS ----
    {
        int row = tid >> 2, quarter = tid & 3;
        bool ok = (m0 + row) < M;
        const uint4* gA = (const uint4*)(A + (size_t)(m0 + row) * 256 + quarter * 64);
        uint4* sA = (uint4*)(As + row * LDA2 + quarter * 64);
        const uint4 z4 = make_uint4(0, 0, 0, 0);
        uint4 v[8];
#pragma unroll
        for (int i = 0; i < 8; ++i) v[i] = ok ? gA[i] : z4;
#pragma unroll
        for (int i = 0; i < 8; ++i) sA[i] = v[i];
    }
    __syncthreads();

    // B fragment base: rows n (in y-strip), cols k
    const unsigned short* gB = Wt + (size_t)(n0 + wn * 32 + l15) * 256 + q * 8;

    bf16x8 b_cur[2], b_nxt[2];
#pragma unroll
    for (int j = 0; j < 2; ++j) {
        b_cur[j] = *(const bf16x8*)(gB + j * 16 * 256);   // z=0, kb=0
        b_nxt[j] = b_cur[j];
    }

#pragma unroll
    for (int z = 0; z < 2; ++z) {
        f32x4 acc[4][2];
#pragma unroll
        for (int i = 0; i < 4; ++i)
#pragma unroll
            for (int j = 0; j < 2; ++j) acc[i][j] = (f32x4){0.f, 0.f, 0.f, 0.f};

#pragma unroll
        for (int kb = 0; kb < 8; ++kb) {
            // prefetch next step's B fragments (crosses z boundary at kb==7, z==0)
            if (!(z == 1 && kb == 7)) {
                int zn = (kb == 7) ? 1 : z;
                int kn = (kb == 7) ? 0 : kb + 1;
#pragma unroll
                for (int j = 0; j < 2; ++j)
                    b_nxt[j] = *(const bf16x8*)(gB + (size_t)zn * 65536 + j * 16 * 256 + kn * 32);
            }
            bf16x8 a[4];
#pragma unroll
            for (int i = 0; i < 4; ++i)
                a[i] = *(const bf16x8*)&As[(i * 16 + l15) * LDA2 + kb * 32 + q * 8];
#pragma unroll
            for (int i = 0; i < 4; ++i)
#pragma unroll
                for (int j = 0; j < 2; ++j)
                    acc[i][j] = __builtin_amdgcn_mfma_f32_16x16x32_bf16(a[i], b_cur[j], acc[i][j], 0, 0, 0);
#pragma unroll
            for (int j = 0; j < 2; ++j) b_cur[j] = b_nxt[j];
        }

        // ---- epilogue for this z: acc -> Cs -> coalesced global stores ----
        const float* bias = z ? bb : ba;
        unsigned short* C = z ? Cb : Ca;
#pragma unroll
        for (int j = 0; j < 2; ++j) {
            int col = wn * 32 + j * 16 + l15;
            float bcol = bias[n0 + col];
#pragma unroll
            for (int i = 0; i < 4; ++i) {
#pragma unroll
                for (int rr = 0; rr < 4; ++rr)
                    Cs[(i * 16 + q * 4 + rr) * LDC2 + col] = f2bf(acc[i][j][rr] + bcol);
            }
        }
        __syncthreads();
        {
            int row = tid >> 2, seg = tid & 3;
            if (m0 + row < M) {
                const uint4* src = (const uint4*)&Cs[row * LDC2 + seg * 32];
                uint4* dst = (uint4*)(C + (size_t)(m0 + row) * 256 + n0 + seg * 32);
#pragma unroll
                for (int i = 0; i < 4; ++i) dst[i] = src[i];   // 4 x 16B = full 32-col segment
            }
        }
        __syncthreads();   // protect Cs before z=1 writes
    }
}

extern "C" void kernel_launch(void* const* d_in, const int* in_sizes, int n_in,
                              void* d_out, int out_size, void* d_ws, size_t ws_size,
                              hipStream_t stream) {
    const float* x    = (const float*)d_in[0];
    const int*   ei   = (const int*)d_in[1];
    const float* Wl1  = (const float*)d_in[2];
    const float* bl1  = (const float*)d_in[3];
    const float* Wr1  = (const float*)d_in[4];
    const float* br1  = (const float*)d_in[5];
    const float* att1 = (const float*)d_in[6];
    const float* bias1= (const float*)d_in[7];
    const float* Wl2  = (const float*)d_in[8];
    const float* bl2  = (const float*)d_in[9];
    const float* Wr2  = (const float*)d_in[10];
    const float* br2  = (const float*)d_in[11];
    const float* att2 = (const float*)d_in[12];
    const float* bias2= (const float*)d_in[13];

    int n = in_sizes[0] / 20;
    int e = in_sizes[1] / 2;
    float* out = (float*)d_out;
    size_t nch = (size_t)n * CH;

    unsigned short* buf0 = (unsigned short*)d_ws;
    unsigned short* buf1 = buf0 + nch;
    unsigned short* hbuf = buf1 + nch;
    unsigned short* wt2  = hbuf + nch;
    int* deg    = (int*)(wt2 + 2 * 65536);
    int* rowptr = deg + n;
    int* cursor = rowptr + n + 1;
    int* bsums  = cursor + n;
    int* csr    = bsums + 64;

    hipMemsetAsync(deg, 0, (size_t)n * sizeof(int), stream);

    gemm1_kernel<<<(n + 63) / 64, 256, 0, stream>>>(x, Wl1, bl1, Wr1, br1, buf0, buf1, n);

    count_deg<<<(e + 255) / 256, 256, 0, stream>>>(ei, deg, e);
    int nb = (n + SCAN_BLOCK - 1) / SCAN_BLOCK;
    scan_block_k<<<nb, SCAN_BLOCK, 0, stream>>>(deg, rowptr, bsums, n);
    scan_tops_k<<<1, 64, 0, stream>>>(bsums, nb);
    scan_fix_k<<<nb, SCAN_BLOCK, 0, stream>>>(rowptr, cursor, deg, bsums, n);
    scatter_k<<<(e + 255) / 256, 256, 0, stream>>>(ei, cursor, csr, e);

    wconv<<<512, 256, 0, stream>>>(Wl2, Wr2, wt2);

    fused_gat1<<<(n + 3) / 4, 256, 0, stream>>>(buf0, buf1, rowptr, csr, att1, bias1, hbuf, n);

    gemm_mfma<<<((n + 63) / 64) * 2, 256, 0, stream>>>(hbuf, wt2, bl2, br2, buf0, buf1, n);

    fused_gat2<<<(n + 3) / 4, 256, 0, stream>>>(buf0, buf1, rowptr, csr, att2, bias2, out, n);
}